// Round 1
// baseline (131.672 us; speedup 1.0000x reference)
//
#include <hip/hip_runtime.h>
#include <hip/hip_bf16.h>
#include <hip/hip_fp16.h>

// Problem constants
#define NT 8192            // tokens
#define NQB 6              // qubits
#define NL 2               // layers
// Attention kernel tiling
#define JSPLIT 16
#define JSLICE (NT / JSPLIT)     // 512 keys per block
#define CHUNK 32                 // keys staged per LDS chunk (one W-MFMA K-group)
#define NCHUNK (JSLICE / CHUNK)  // 16
#define IPW 16                   // query rows per wave (1 rowtile)
#define WPB 4                    // waves per block
#define IPB (IPW * WPB)          // 64 rows per block
#define NBI (NT / IPB)           // 128 i-blocks
#define WSTRIDE 40               // fp16 units per W-transpose row (80B: 16B-aligned, bank-spread)

typedef _Float16 f16x8 __attribute__((ext_vector_type(8)));
typedef float f32x4 __attribute__((ext_vector_type(4)));

static __device__ __forceinline__ unsigned int pack_h2(float a, float b) {
  unsigned short lo = __builtin_bit_cast(unsigned short, (_Float16)a);
  unsigned short hi = __builtin_bit_cast(unsigned short, (_Float16)b);
  return (unsigned int)lo | ((unsigned int)hi << 16);
}

// one CNOT's index map: src(p) = p ^ (bit_c(p) ? mask_t : 0)  (an involution)
static __device__ __forceinline__ int cnot_src(int p, int q) {
  const int mc = 1 << (5 - q);
  const int mt = 1 << (5 - ((q + 1) % NQB));
  return (p & mc) ? (p ^ mt) : p;
}

// direct-to-LDS 16B async copy (gfx950). LDS dest is wave-uniform base + lane*16.
#define GLOAD_LDS16(g, l)                                      \
  __builtin_amdgcn_global_load_lds(                            \
      (const __attribute__((address_space(1))) void*)(g),      \
      (__attribute__((address_space(3))) void*)(l), 16, 0, 0)

// ---------------------------------------------------------------------------
// Kernel 1: statevector prep, product-state form (verified earlier rounds).
// One wave per (token, set); lane = basis state. Now emits fp16:
//  set0: Are linear  [tok][u32 e]        (fp16 re,im packed per u32)
//  set1: Bk  SWIZZLED: uint4 unit u stored at u^(tok&15)  -> conflict-free
//        ds_read after a LINEAR global_load_lds stage (swizzle baked in global)
//  set2: Vt [16][NT] fp16: rows 0..5 = <Z_q> hi, 6 = 1.0 (den), 7 = 0,
//        rows 8..13 = <Z_q> residual (lo), 14..15 = 0.  hi/lo split keeps
//        V at ~f32 precision through the fp16 W-MFMA.
// ---------------------------------------------------------------------------
__global__ __launch_bounds__(256) void prep_kernel(
    const float* __restrict__ x, const float* __restrict__ pq,
    const float* __restrict__ pk, const float* __restrict__ pv,
    unsigned int* __restrict__ Are, unsigned int* __restrict__ Bk,
    unsigned short* __restrict__ Vt)
{
  const int wid  = blockIdx.x * 4 + (threadIdx.x >> 6);
  const int lane = threadIdx.x & 63;
  const int set  = wid >> 13;          // / 8192
  const int tok  = wid & (NT - 1);
  const float* pp = (set == 0) ? pq : ((set == 1) ? pk : pv);

  // sigma(l) = src_0(src_1(...src_5(l)))   [final[l] = old[sigma(l)]]
  int m = lane;
#pragma unroll
  for (int q = 5; q >= 0; --q) m = cnot_src(m, q);
  // sigma^{-1}(l) = src_5(src_4(...src_0(l)))
  int inv = lane;
#pragma unroll
  for (int q = 0; q < 6; ++q) inv = cnot_src(inv, q);

  // product state (through layer-0) evaluated at index m
  float R = 1.f, phi = 0.f;
#pragma unroll
  for (int q = 0; q < 6; ++q) {
    float s, c;
    __sincosf(0.5f * (x[tok * NQB + q] + pp[q * 2 + 0]), &s, &c);
    const float bh = 0.5f * pp[q * 2 + 1];
    if ((m >> (5 - q)) & 1) { R *= s; phi += bh; }
    else                    { R *= c; phi -= bh; }
  }
  float sp, cp;
  __sincosf(phi, &sp, &cp);
  float re = R * cp, im = R * sp;

  // layer-1 RYs (entangled now -> shuffles)
#pragma unroll
  for (int q = 0; q < 6; ++q) {
    const int mask = 1 << (5 - q);
    float s, c;
    __sincosf(0.5f * pp[2 * NQB + q * 2 + 0], &s, &c);
    const float pre = __shfl_xor(re, mask, 64);
    const float pim = __shfl_xor(im, mask, 64);
    const float se = (lane & mask) ? s : -s;
    re = fmaf(se, pre, c * re);
    im = fmaf(se, pim, c * im);
  }
  // layer-1 RZs combined into one phase per lane
  float phi2 = 0.f;
#pragma unroll
  for (int q = 0; q < 6; ++q) {
    const float bh = 0.5f * pp[2 * NQB + q * 2 + 1];
    phi2 += (lane & (1 << (5 - q))) ? bh : -bh;
  }
  float s2, c2;
  __sincosf(phi2, &s2, &c2);
  const float fre = re * c2 - im * s2;
  const float fim = re * s2 + im * c2;

  if (set == 0) {
    Are[tok * 64 + inv] = pack_h2(fre, fim);     // [qr, qi] fp16, linear
  } else if (set == 1) {
    // XOR-preswizzle per uint4 unit so attn's linear global_load_lds + swizzled
    // ds_read is bank-uniform: u32 index e stored at ((e>>2)^(tok&15))*4 | (e&3)
    const int sidx = ((((inv >> 2) ^ (tok & 15)) << 2) | (inv & 3));
    Bk[tok * 64 + sidx] = pack_h2(fre, fim);
  } else {
    const float prob = fre * fre + fim * fim;    // prob of final basis index 'inv'
    float vq[NQB];
#pragma unroll
    for (int q = 0; q < NQB; ++q) {
      float v = (inv & (1 << (5 - q))) ? -prob : prob;  // sign = 1-2*bit
#pragma unroll
      for (int off = 1; off < 64; off <<= 1) v += __shfl_xor(v, off, 64);
      vq[q] = v;
    }
    if (lane < 16) {
      const int q = lane & 7;
      float sel = vq[0];
      if (q == 1) sel = vq[1];
      if (q == 2) sel = vq[2];
      if (q == 3) sel = vq[3];
      if (q == 4) sel = vq[4];
      if (q == 5) sel = vq[5];
      if (q == 6) sel = 1.0f;                    // ones column -> den via MFMA
      if (q == 7) sel = 0.0f;
      float outv;
      if (lane < 8) {
        outv = sel;                              // hi part
      } else {
        const float hi = (float)(_Float16)sel;   // lo part = residual
        outv = (q < 6) ? (sel - hi) : 0.0f;
      }
      Vt[lane * NT + tok] = __builtin_bit_cast(unsigned short, (_Float16)outv);
    }
  }
}

// ---------------------------------------------------------------------------
// Kernel 2: fused swap-test attention, MFMA end-to-end.
//  - swapped QK^T: mfma(K, Q) so each lane's D regs = 4 CONSECUTIVE keys for
//    one query row -> W transpose to A-fragment layout is 1 ds_write_b64 +
//    1 ds_read_b128 per lane (per-wave wbuf, no barrier).
//  - softmax num/den via second MFMA: acc = W(16x32 fp16) x [V|1|Vlo](32x16)
//    -> kills 7 fmaf/logit, the 448-op shuffle tail, and 52 acc VGPRs.
//  - staging: global_load_lds double-buffer, counted vmcnt(2) + raw s_barrier
//    (next chunk's loads stay in flight across the barrier).
//  - kbuf reads use the global preswizzle: per-lane offset ((s*4+quad)^col)*16,
//    compile-time per lane -> 32-bank-uniform, zero inner VALU cost.
// MFMA 16x16x32 layouts (A and B frags are lane-identical):
//   A/B: row/col = lane&15, k = (lane>>4)*8 + j;  D: col = lane&15, row = (lane>>4)*4 + r
// ---------------------------------------------------------------------------
__global__ __launch_bounds__(256, 2) void attn_kernel(
    const uint4* __restrict__ Are, const uint4* __restrict__ Bk,
    const unsigned short* __restrict__ Vt, float* __restrict__ part)
{
  __shared__ uint4 kbuf[2][CHUNK * 16];                       // 16 KiB, LINEAR dest
  __shared__ __align__(16) unsigned short wbuf[WPB][16][WSTRIDE]; // 5 KiB W transpose

  const int tid  = threadIdx.x;
  const int lane = tid & 63;
  const int wave = tid >> 6;
  const int col  = lane & 15;
  const int quad = lane >> 4;

  const int ib = blockIdx.x & (NBI - 1);
  const int js = blockIdx.x >> 7;                 // / NBI (NBI == 128)
  const int ibase = ib * IPB + wave * IPW;
  const int jbase0 = js * JSLICE;

  // Query fragments (MFMA B operand): this wave's 16 rows, resident all sweep.
  // qIm derived in-register: (qr,qi) -> (qi,-qr) per packed u32.
  f16x8 qRe[4], qIm[4];
  {
    const uint4* pr = Are + (ibase + col) * 16 + quad;
#pragma unroll
    for (int s = 0; s < 4; ++s) {
      const uint4 u = pr[s * 4];
      uint4 w;
      w.x = ((u.x << 16) | (u.x >> 16)) ^ 0x80000000u;
      w.y = ((u.y << 16) | (u.y >> 16)) ^ 0x80000000u;
      w.z = ((u.z << 16) | (u.z >> 16)) ^ 0x80000000u;
      w.w = ((u.w << 16) | (u.w >> 16)) ^ 0x80000000u;
      qRe[s] = __builtin_bit_cast(f16x8, u);
      qIm[s] = __builtin_bit_cast(f16x8, w);
    }
  }

  // per-lane swizzled kbuf byte offsets: u' = (s*4+quad) ^ col  (key&15 == col)
  int koff[4];
#pragma unroll
  for (int s = 0; s < 4; ++s) koff[s] = (((s * 4 + quad) ^ col) << 4);

  f32x4 acc = {0.f, 0.f, 0.f, 0.f};

  // stage chunk c (8 KiB = 32 keys x 256B) into kbuf[buf]: 2 x 1KiB per wave
  auto stage = [&](int buf, int c) {
#pragma unroll
    for (int r = 0; r < 2; ++r) {
      const int slot = wave * 2 + r;              // 0..7, 64 uint4 each
      GLOAD_LDS16(Bk + (size_t)(jbase0 + c * CHUNK) * 16 + slot * 64 + lane,
                  &kbuf[buf][slot * 64]);
    }
  };

  stage(0, 0);

#pragma unroll 1
  for (int c = 0; c < NCHUNK; ++c) {
    const int cur = c & 1;
    const int jb = jbase0 + c * CHUNK;
    // V fragment for this 32-key group (B operand; issue before next stage so
    // the counted vmcnt covers it too)
    const f16x8 vb = *(const f16x8*)(Vt + (size_t)col * NT + jb + quad * 8);
    if (c + 1 < NCHUNK) {
      stage(cur ^ 1, c + 1);
      asm volatile("s_waitcnt vmcnt(2)" ::: "memory");  // cur chunk landed; next's 2 stay in flight
    } else {
      asm volatile("s_waitcnt vmcnt(0)" ::: "memory");
    }
    __builtin_amdgcn_s_barrier();                 // all waves' stage(cur) landed

#pragma unroll
    for (int ct = 0; ct < 2; ++ct) {
      const char* kb = (const char*)kbuf[cur] + (ct * 16 + col) * 256;
      f16x8 bfr[4];
#pragma unroll
      for (int s = 0; s < 4; ++s) bfr[s] = *(const f16x8*)(kb + koff[s]);
      f32x4 aR = {0.f, 0.f, 0.f, 0.f};
      f32x4 aI = {0.f, 0.f, 0.f, 0.f};
#pragma unroll
      for (int s = 0; s < 4; ++s) {
        aR = __builtin_amdgcn_mfma_f32_16x16x32_f16(bfr[s], qRe[s], aR, 0, 0, 0);
        aI = __builtin_amdgcn_mfma_f32_16x16x32_f16(bfr[s], qIm[s], aI, 0, 0, 0);
      }
      // lane holds keys ct*16+quad*4..+3 for query row 'col'; f in [0,1]
      const float w0 = __expf(aR[0] * aR[0] + aI[0] * aI[0]);
      const float w1 = __expf(aR[1] * aR[1] + aI[1] * aI[1]);
      const float w2 = __expf(aR[2] * aR[2] + aI[2] * aI[2]);
      const float w3 = __expf(aR[3] * aR[3] + aI[3] * aI[3]);
      *(uint2*)&wbuf[wave][col][ct * 16 + quad * 4] =
          make_uint2(pack_h2(w0, w1), pack_h2(w2, w3));
    }
    // W-MFMA: A = W[qrow][key0..31], B = Vt[q][key0..31]  (per-wave, DS in-order)
    const f16x8 wA = *(const f16x8*)&wbuf[wave][col][quad * 8];
    acc = __builtin_amdgcn_mfma_f32_16x16x32_f16(wA, vb, acc, 0, 0, 0);
    __builtin_amdgcn_s_barrier();                 // all reads of kbuf[cur] done
  }

  // combine hi (cols 0..6) + lo (cols 8..14) and write partials
  float res[4];
#pragma unroll
  for (int r = 0; r < 4; ++r) res[r] = acc[r] + __shfl_xor(acc[r], 8, 64);
  if (col < 8) {
    float* p = part + ((size_t)(js * NT + ibase + quad * 4)) * 8 + col;
#pragma unroll
    for (int r = 0; r < 4; ++r) p[r * 8] = res[r];  // p[col] for row +r; col6=den, col7=0
  }
}

// ---------------------------------------------------------------------------
// Kernel 3: combine the 16 j-slice partials, normalize, emit float32.
// ---------------------------------------------------------------------------
__global__ __launch_bounds__(256) void combine_kernel(
    const float* __restrict__ part, float* __restrict__ out)
{
  const int row = blockIdx.x * 256 + threadIdx.x;
  float acc[7] = {0.f, 0.f, 0.f, 0.f, 0.f, 0.f, 0.f};
#pragma unroll
  for (int js = 0; js < JSPLIT; ++js) {
    const float* p = part + ((size_t)(js * NT + row)) * 8;
#pragma unroll
    for (int q = 0; q < 7; ++q) acc[q] += p[q];
  }
  const float inv = 1.0f / acc[6];
#pragma unroll
  for (int q = 0; q < 6; ++q)
    out[row * 6 + q] = acc[q] * inv;
}

// ---------------------------------------------------------------------------
// Workspace layout (bytes):
//   Are  @ 0        : 8192*64*4 = 2 MiB   (fp16 pairs packed in u32, linear)
//   Bk   @ 2 MiB    : 2 MiB               (fp16 pairs, uint4-XOR-preswizzled)
//   Vt   @ 4 MiB    : 16*8192*2 = 256 KiB (fp16 [V|1|Vlo] rows)
//   part @ 4.25 MiB : 16*8192*8*4 = 4 MiB
//   total 8.25 MiB  (same footprint as previous round)
// ---------------------------------------------------------------------------
extern "C" void kernel_launch(void* const* d_in, const int* in_sizes, int n_in,
                              void* d_out, int out_size, void* d_ws, size_t ws_size,
                              hipStream_t stream) {
  const float* x  = (const float*)d_in[0];
  const float* pq = (const float*)d_in[1];
  const float* pk = (const float*)d_in[2];
  const float* pv = (const float*)d_in[3];
  char* ws = (char*)d_ws;
  unsigned int*   Are = (unsigned int*)(ws);
  unsigned int*   Bk  = (unsigned int*)(ws + (size_t)(2u << 20));
  unsigned short* Vt  = (unsigned short*)(ws + (size_t)(4u << 20));
  float*          prt = (float*)(ws + (size_t)(4u << 20) + (size_t)(256u << 10));

  prep_kernel<<<(NT * 3) / 4, 256, 0, stream>>>(x, pq, pk, pv, Are, Bk, Vt);
  attn_kernel<<<NBI * JSPLIT, 256, 0, stream>>>((const uint4*)Are, (const uint4*)Bk,
                                                Vt, prt);
  combine_kernel<<<NT / 256, 256, 0, stream>>>(prt, (float*)d_out);
}